// Round 19
// baseline (286.855 us; speedup 1.0000x reference)
//
#include <hip/hip_runtime.h>
#include <hip/hip_bf16.h>
#include <stdint.h>

#define BB 16
#define NZ 2048
#define NE 2048
#define DD 512

typedef unsigned short u16;
typedef __attribute__((ext_vector_type(8))) _Float16 f16x8;  // 8 fp16 = 4 VGPR
typedef __attribute__((ext_vector_type(8))) short s16x8;
typedef __attribute__((ext_vector_type(4))) float f32x4;

// ---------- helpers ----------
__device__ __forceinline__ u16 f2h(float f) {
  _Float16 h = (_Float16)f;                 // v_cvt_f16_f32, RNE
  return __builtin_bit_cast(u16, h);
}

__device__ __forceinline__ float h2f(u16 h) {
  return (float)__builtin_bit_cast(_Float16, h);
}

__device__ __forceinline__ void gload_lds16(const void* g, void* l) {
  auto gp = (const __attribute__((address_space(1))) uint32_t*)g;
  auto lp = (__attribute__((address_space(3))) uint32_t*)l;
  __builtin_amdgcn_global_load_lds(gp, lp, 16, 0, 0);
}

#define FENCE() asm volatile("" ::: "memory")
#define BARRIER() do { FENCE(); __builtin_amdgcn_s_barrier(); FENCE(); } while (0)
#define WAIT_LGKM0() asm volatile("s_waitcnt lgkmcnt(0)" ::: "memory")
#define WAIT_VM(n) asm volatile("s_waitcnt vmcnt(" #n ")" ::: "memory")

// ---------- f32 -> fp16 bulk convert (16B stores) ----------
__global__ void k_cvt(const float* __restrict__ in, u16* __restrict__ out, int n8) {
  int i = blockIdx.x * blockDim.x + threadIdx.x;
  int stride = gridDim.x * blockDim.x;
  for (; i < n8; i += stride) {
    float4 v0 = ((const float4*)in)[i * 2];
    float4 v1 = ((const float4*)in)[i * 2 + 1];
    s16x8 o;
    o[0] = (short)f2h(v0.x); o[1] = (short)f2h(v0.y);
    o[2] = (short)f2h(v0.z); o[3] = (short)f2h(v0.w);
    o[4] = (short)f2h(v1.x); o[5] = (short)f2h(v1.y);
    o[6] = (short)f2h(v1.z); o[7] = (short)f2h(v1.w);
    ((s16x8*)out)[i] = o;
  }
}

// ---------- M[512x512] -> Mt fp16 (Mt[e][d] = M[d][e]) ----------
__global__ void k_mt(const float* __restrict__ M, u16* __restrict__ Mt) {
  __shared__ float t[32][33];
  int bx = blockIdx.x * 32;  // e range
  int by = blockIdx.y * 32;  // d range
  for (int r = 0; r < 32; r += 8)
    t[threadIdx.y + r][threadIdx.x] = M[(size_t)(by + threadIdx.y + r) * DD + bx + threadIdx.x];
  __syncthreads();
  for (int r = 0; r < 32; r += 8)
    Mt[(size_t)(bx + threadIdx.y + r) * DD + by + threadIdx.x] = f2h(t[threadIdx.x][threadIdx.y + r]);
}

// ---------- k_et: eT'[b][d][m] = fp16( eH[b][m][d] * 2048 / cs[b][m] ) --------
// 64x64 tile, fully 16B-vectorized both sides; XOR-block-permuted LDS
// (r16-verified).
__global__ void k_et(const u16* __restrict__ eH, const float* __restrict__ cs,
                     u16* __restrict__ eT) {
  __shared__ u16 sm[64 * 72];
  const int t = threadIdx.x;
  const int b = blockIdx.z;
  const int d0 = blockIdx.x * 64;
  const int m0 = blockIdx.y * 64;
  const u16* eb = eH + (size_t)b * NE * DD;
  const float* csb = cs + (size_t)b * NE;
#pragma unroll
  for (int it = 0; it < 2; ++it) {
    int idx = it * 256 + t;           // 0..511
    int ml = idx >> 3;                // 0..63
    int dc = idx & 7;                 // 8-d chunk
    s16x8 v = *(const s16x8*)(eb + (size_t)(m0 + ml) * DD + d0 + dc * 8);
    float sc = 2048.0f / csb[m0 + ml];
    int bl = ml >> 3, il = ml & 7;
#pragma unroll
    for (int j = 0; j < 8; ++j) {
      int d = dc * 8 + j;             // d&7 == j
      int pc = ((bl ^ j) << 3) + il;  // permuted col
      sm[d * 72 + pc] = f2h(h2f((u16)v[j]) * sc);
    }
  }
  __syncthreads();
  u16* eTb = eT + (size_t)b * DD * NE;
#pragma unroll
  for (int it = 0; it < 2; ++it) {
    int idx = it * 256 + t;
    int dl = idx >> 3;                // 0..63
    int mc = idx & 7;                 // 8-m chunk
    int pb = mc ^ (dl & 7);           // permuted block
    s16x8 v = *(const s16x8*)&sm[dl * 72 + pb * 8];
    *(s16x8*)(eTb + (size_t)(d0 + dl) * NE + m0 + mc * 8) = v;
  }
}

// ---------- 128x128 tile, BK=32, 2-wave block, 2-slot ring, 4 blocks/CU ------
// C = A[M x K] * Bt[N x K]^T.  128 threads = 2 waves; per-wave tile 128x64 =
// 8m x 4n frags of 16x16x32 -> 12 ds_read_b128 per 32 MFMA (0.375, r18 was
// 0.5).  LDS 32 KiB = 2 ring slots x 16 KiB (A 8K @ +0, B 8K @ +8192),
// linear 64-B rows + XOR chunk swizzle q = cL ^ ((r>>1)&3) [coalesced
// global_load_lds AND conflict-free ds_read_b128, r10-r18 verified].
// launch_bounds(128,2) => 4 resident 2-wave groups/CU (vs r16's 3 x 4-wave):
// more independent groups + cheaper barriers fill the sync dead time.
// Step t: 12 ds_read slot t&1 + 32 MFMA; lgkm0; BAR1; stage(t+1)->other slot
// [WAR-safe: last read at t-1, 3 barriers ago]; WAIT_VM(0) [tile t+1 landed;
// exposure covered by 3 sibling groups — m97 mechanism]; BAR2; swap.
// EPI: 0 = fp16 out; 1 = exp(sigmoid(x)) fp16 out + colsum atomics; 2 = f32/2048
template<int EPI, int KDIM>
__global__ __launch_bounds__(128, 2) void k_gemm(
    const u16* __restrict__ A, const u16* __restrict__ Bt, void* __restrict__ Cp,
    int Ndim, long long sAb, long long sBb, long long sCb,
    float* __restrict__ colsum, int csld)
{
  extern __shared__ char lds[];
  constexpr int NT = KDIM / 32;

  // bijective XCD-aware swizzle (nwg % 8 == 0 for all our launches)
  const int gx = gridDim.x, gy = gridDim.y;
  const int nwg = gx * gy * gridDim.z;
  const int hid = blockIdx.x + gx * (blockIdx.y + gy * blockIdx.z);
  const int logical = (hid & 7) * (nwg >> 3) + (hid >> 3);
  const int bx = logical % gx;
  const int rem0 = logical / gx;
  const int by = rem0 % gy;
  const int bz = rem0 / gy;

  const int tid = threadIdx.x;     // 0..127
  const int lane = tid & 63;
  const int wid = tid >> 6;        // 0..1 (wave owns cols wid*64)

  const int row0 = by * 128;
  const int col0 = bx * 128;

  const u16* Ab = A + (long long)bz * sAb;
  const u16* Bb = Bt + (long long)bz * sBb;

  // staging sources: instr c covers LDS chunks idx = c*128 + tid (0..511);
  // r = idx>>2, cL = idx&3, source chunk q = cL ^ ((r>>1)&3)  (in-row permute
  // -> coalescing preserved; matches the ds_read-side XOR)
  const u16* pA[4]; const u16* pB[4];
#pragma unroll
  for (int c = 0; c < 4; ++c) {
    int idx = c * 128 + tid;
    int r = idx >> 2;
    int cL = idx & 3;
    int q = cL ^ ((r >> 1) & 3);
    pA[c] = Ab + (long long)(row0 + r) * KDIM + q * 8;
    pB[c] = Bb + (long long)(col0 + r) * KDIM + q * 8;
  }

  // stage current pointer position into slot s, then advance by 32 (one K-step)
  auto stage = [&](char* s) {
#pragma unroll
    for (int c = 0; c < 4; ++c) {
      gload_lds16(pA[c], s + (c * 128 + wid * 64) * 16);
      pA[c] += 32;
    }
#pragma unroll
    for (int c = 0; c < 4; ++c) {
      gload_lds16(pB[c], s + 8192 + (c * 128 + wid * 64) * 16);
      pB[c] += 32;
    }
  };

  // per-lane invariant fragment offsets:
  // c4 = (lane>>4) ^ ((p15>>1)&3) is m/n-invariant (m*16>>1 ≡ 0 mod 4)
  const int p15 = lane & 15;
  const int c4 = (lane >> 4) ^ ((p15 >> 1) & 3);
  const int laneA = p15 * 64 + c4 * 16;                       // + m*1024
  const int laneB = 8192 + wid * 4096 + p15 * 64 + c4 * 16;   // + n*1024

  f32x4 acc[8][4] = {};

  // 2-slot ring
  char* sl0 = lds;
  char* sl1 = lds + 16384;

  stage(sl0);        // tile 0
  WAIT_VM(0);
  BARRIER();

  for (int t = 0; t < NT; ++t) {
    f16x8 af[8], bf[4];
#pragma unroll
    for (int m = 0; m < 8; ++m) af[m] = *(const f16x8*)(sl0 + laneA + m * 1024);
#pragma unroll
    for (int n = 0; n < 4; ++n) bf[n] = *(const f16x8*)(sl0 + laneB + n * 1024);
#pragma unroll
    for (int m = 0; m < 8; ++m)
#pragma unroll
      for (int n = 0; n < 4; ++n)
        acc[m][n] = __builtin_amdgcn_mfma_f32_16x16x32_f16(af[m], bf[n], acc[m][n], 0, 0, 0);

    if (t + 1 < NT) {
      WAIT_LGKM0();                   // reads of sl0 complete
      BARRIER();                      // #1: all waves' reads done
      stage(sl1);                     // tile t+1 (slot last read at t-1)
      WAIT_VM(0);                     // tile t+1 landed (covered by siblings)
      BARRIER();                      // #2: visible to all waves
    }
    char* tmp = sl0; sl0 = sl1; sl1 = tmp;
  }

  __syncthreads();   // final reads drained; LDS free for epilogue reuse

  // C/D frag layout: col = lane&15, row = (lane>>4)*4 + j
  const int rr = (lane >> 4) * 4;
  const int cc = lane & 15;
  const int grow = row0;                    // wave covers all 128 rows
  const int gcol = col0 + wid * 64;

  if constexpr (EPI == 0 || EPI == 1) {
    // stage u16 128x64 wave-tile in LDS (16 KiB/wave), coalesced dwordx4 out
    char* wb = lds + wid * 16384;
    float csum[4] = {0.f, 0.f, 0.f, 0.f};
#pragma unroll
    for (int m = 0; m < 8; ++m)
#pragma unroll
      for (int n = 0; n < 4; ++n)
#pragma unroll
        for (int j = 0; j < 4; ++j) {
          float x = acc[m][n][j];
          float v;
          if constexpr (EPI == 1) {
            float s = 1.f / (1.f + __expf(-x));   // sigmoid
            v = __expf(s);                        // in (1, e)
            csum[n] += v;
          } else {
            v = x;
          }
          int rl = m * 16 + rr + j;              // 0..127
          int col = n * 16 + cc;                 // 0..63
          int chunk = (col >> 3) ^ (rl & 7);     // bank swizzle
          *(u16*)(wb + rl * 128 + chunk * 16 + ((col * 2) & 15)) = f2h(v);
        }
    if constexpr (EPI == 1) {
#pragma unroll
      for (int n = 0; n < 4; ++n) {
        float v = csum[n];
        v += __shfl_xor(v, 16, 64);
        v += __shfl_xor(v, 32, 64);
        if ((lane >> 4) == 0)
          atomicAdd(&colsum[(long long)bz * csld + gcol + n * 16 + cc], v);
      }
    }
    __syncthreads();   // cross-lane LDS write->read ordering (r6 fix)
    u16* C = (u16*)Cp + (long long)bz * sCb;
#pragma unroll
    for (int s = 0; s < 16; ++s) {
      int rl = (lane >> 3) + s * 8;              // 0..127
      int chunk = (lane & 7) ^ (rl & 7);
      f16x8 v = *(const f16x8*)(wb + rl * 128 + chunk * 16);
      *(f16x8*)(&C[(long long)(grow + rl) * Ndim + gcol + (lane & 7) * 8]) = v;
    }
  } else {
    // f32 out: two 64-row passes, 16 KiB/wave each, coalesced dwordx4
    float* C = (float*)Cp + (long long)bz * sCb;
    char* wb = lds + wid * 16384;
#pragma unroll
    for (int h = 0; h < 2; ++h) {
      if (h) __syncthreads();                    // pass-0 reads done before overwrite
#pragma unroll
      for (int mm = 0; mm < 4; ++mm) {
        int m = h * 4 + mm;
#pragma unroll
        for (int n = 0; n < 4; ++n)
#pragma unroll
          for (int j = 0; j < 4; ++j) {
            int rl = mm * 16 + rr + j;           // 0..63
            int col = n * 16 + cc;               // 0..63
            int chunk = (col >> 2) ^ (rl & 15);  // 16 chunks/row
            *(float*)(wb + rl * 256 + chunk * 16 + ((col * 4) & 15)) =
                acc[m][n][j] * (1.0f / 2048.0f);
          }
      }
      __syncthreads();                           // write->read ordering
#pragma unroll
      for (int s = 0; s < 16; ++s) {
        int rl = (lane >> 4) + s * 4;            // 0..63
        int chunk = (lane & 15) ^ (rl & 15);
        f32x4 v = *(const f32x4*)(wb + rl * 256 + chunk * 16);
        *(f32x4*)(&C[(long long)(grow + h * 64 + rl) * Ndim + gcol + (lane & 15) * 4]) = v;
      }
    }
  }
}

// ---------- launch ----------
// ws layout (bytes):
//   S      @ 0          : 16*2048*2048*2 = 134217728
//   zM     @ 134217728  : 16*2048*512*2  =  33554432
//   zH/eT  @ 167772160  :                  33554432   (z fp16; reused as eT)
//   eH     @ 201326592  :                  33554432
//   Mt     @ 234881024  :                    524288
//   colsum @ 235405312  : 16*2048*4      =    131072
extern "C" void kernel_launch(void* const* d_in, const int* in_sizes, int n_in,
                              void* d_out, int out_size, void* d_ws, size_t ws_size,
                              hipStream_t stream) {
  const float* z = (const float*)d_in[0];
  const float* e = (const float*)d_in[1];
  const float* M = (const float*)d_in[2];
  float* out = (float*)d_out;
  char* ws = (char*)d_ws;

  u16* S    = (u16*)(ws + 0LL);
  u16* zM   = (u16*)(ws + 134217728LL);
  u16* zH   = (u16*)(ws + 167772160LL);
  u16* eH   = (u16*)(ws + 201326592LL);
  u16* Mt   = (u16*)(ws + 234881024LL);
  float* cs = (float*)(ws + 235405312LL);

  hipMemsetAsync(cs, 0, (size_t)BB * NE * sizeof(float), stream);

  k_cvt<<<4096, 256, 0, stream>>>(z, zH, BB * NZ * DD / 8);
  k_cvt<<<4096, 256, 0, stream>>>(e, eH, BB * NE * DD / 8);
  k_mt<<<dim3(16, 16), dim3(32, 8), 0, stream>>>(M, Mt);

  // zM[32768 x 512] = zH @ Mt^T   (batch folded into rows); 1024 blocks
  k_gemm<0, 512><<<dim3(DD / 128, (BB * NZ) / 128, 1), 128, 32768, stream>>>(
      zH, Mt, zM, DD, 0LL, 0LL, 0LL, nullptr, 0);

  // S[b] = exp(sigmoid(zM[b] @ eH[b]^T)) ; colsum atomics; 4096 blocks
  k_gemm<1, 512><<<dim3(NE / 128, NZ / 128, BB), 128, 32768, stream>>>(
      zM, eH, S, NE,
      (long long)NZ * DD, (long long)NE * DD, (long long)NZ * NE, cs, NE);

  // eT'[b][d][m] = fp16(eH[b][m][d] * 2048 / colsum[b][m])   (reuses zH region)
  u16* eT = zH;
  k_et<<<dim3(DD / 64, NE / 64, BB), 256, 0, stream>>>(eH, cs, eT);

  // out[b] = (S[b] @ eT[b]^T) / 2048 ; 1024 blocks
  k_gemm<2, 2048><<<dim3(DD / 128, NZ / 128, BB), 128, 32768, stream>>>(
      S, eT, out, DD,
      (long long)NZ * NE, (long long)DD * NE, (long long)NZ * DD, nullptr, 0);
}